// Round 9
// baseline (435.474 us; speedup 1.0000x reference)
//
#include <hip/hip_runtime.h>
#include <hip/hip_fp16.h>
#include <math.h>

#define BATCH 8
#define SCAN_T 256
#define SCAN_E 8
#define SCAN_TILE (SCAN_T * SCAN_E)   // 2048 elems per scan block

union H2U { __half2 h; unsigned u; };

// Pack two int32 into one int64 (little-endian: lo lands at col[p], hi at col[p+1]).
__device__ __forceinline__ long long pack2(int lo, int hi) {
    return (long long)(((unsigned long long)(unsigned)hi << 32) | (unsigned)lo);
}

// ---------------- count + repack fused ----------------
// Blocks [0, cntBlocks): PURE atomic histogram (critical path, launched first).
//   cnt[v] += 2 per corner; rank[corner] = pre-add value (even), coalesced store.
// Remaining blocks: repack vert [B][N][3] fp32 -> vh [N][B] half4 (uint2, 8B).
// Repack streaming rides the memory pipe the atomic-latency-bound count waves
// leave idle (R7: fusion costs +20us on count but removes 30us from fill).
__global__ void count_repack_kernel(const int* __restrict__ faces,
                                    int* __restrict__ cnt,
                                    int* __restrict__ rank,
                                    const float* __restrict__ vert,
                                    uint2* __restrict__ vh,
                                    int N, int F, int cntBlocks) {
    if ((int)blockIdx.x < cntBlocks) {
        int f = blockIdx.x * blockDim.x + threadIdx.x;
        if (f >= F) return;
        int i = faces[3 * f + 0];
        int j = faces[3 * f + 1];
        int k = faces[3 * f + 2];
        rank[3 * f + 0] = atomicAdd(&cnt[i], 2);
        rank[3 * f + 1] = atomicAdd(&cnt[j], 2);
        rank[3 * f + 2] = atomicAdd(&cnt[k], 2);
    } else {
        int u = (blockIdx.x - cntBlocks) * blockDim.x + threadIdx.x;
        if (u >= N * BATCH) return;
        int v = u >> 3;
        int b = u & 7;
        size_t src = ((size_t)b * N + v) * 3;
        H2U xy, zw;
        xy.h = __floats2half2_rn(vert[src], vert[src + 1]);
        zw.h = __floats2half2_rn(vert[src + 2], 0.0f);
        uint2 w; w.x = xy.u; w.y = zw.u;
        vh[u] = w;   // u == v*8 + b
    }
}

// ---------------- scan: two parallel passes (R6-proven, ~25us total) ----------------
// R7's single-pass decoupled lookback was ~85us: 245 serially-dependent L2
// round-trips beat two parallel 2MB passes only at much larger N.
__global__ void scan_sums_kernel(const int* __restrict__ cnt, int* __restrict__ bsums, int N) {
    __shared__ int sh[SCAN_T];
    int base = blockIdx.x * SCAN_TILE + threadIdx.x * SCAN_E;
    int s = 0;
    #pragma unroll
    for (int e = 0; e < SCAN_E; ++e)
        if (base + e < N) s += cnt[base + e];
    sh[threadIdx.x] = s;
    __syncthreads();
    for (int d = SCAN_T / 2; d > 0; d >>= 1) {
        if (threadIdx.x < (unsigned)d) sh[threadIdx.x] += sh[threadIdx.x + d];
        __syncthreads();
    }
    if (threadIdx.x == 0) bsums[blockIdx.x] = sh[0];
}

__global__ void scan_apply_kernel(const int* __restrict__ cnt, int* __restrict__ off,
                                  const int* __restrict__ bsums, int N, int nb) {
    __shared__ int shb[SCAN_T];
    __shared__ int sh[SCAN_T];
    int bv = ((int)threadIdx.x < nb) ? bsums[threadIdx.x] : 0;
    shb[threadIdx.x] = bv;
    __syncthreads();
    for (int d = 1; d < SCAN_T; d <<= 1) {
        int t = (threadIdx.x >= (unsigned)d) ? shb[threadIdx.x - d] : 0;
        __syncthreads();
        shb[threadIdx.x] += t;
        __syncthreads();
    }
    int block_prefix = (blockIdx.x > 0) ? shb[blockIdx.x - 1] : 0;

    int base = blockIdx.x * SCAN_TILE + threadIdx.x * SCAN_E;
    int vals[SCAN_E];
    int s = 0;
    #pragma unroll
    for (int e = 0; e < SCAN_E; ++e) {
        int v = (base + e < N) ? cnt[base + e] : 0;
        vals[e] = v; s += v;
    }
    sh[threadIdx.x] = s;
    __syncthreads();
    for (int d = 1; d < SCAN_T; d <<= 1) {
        int t = (threadIdx.x >= (unsigned)d) ? sh[threadIdx.x - d] : 0;
        __syncthreads();
        sh[threadIdx.x] += t;
        __syncthreads();
    }
    int excl = block_prefix + ((threadIdx.x > 0) ? sh[threadIdx.x - 1] : 0);
    #pragma unroll
    for (int e = 0; e < SCAN_E; ++e) {
        if (base + e < N) off[base + e] = excl;
        excl += vals[e];
    }
}

// ---------------- pure fill (atomic-free; R4-proven) ----------------
// col stores are write-once no-reuse -> non-temporal (as packed int64) to keep
// L2 for off/vh.
__global__ void fill_kernel(const int* __restrict__ faces, const int* __restrict__ off,
                            const int* __restrict__ rank, int* __restrict__ col, int F) {
    int f = blockIdx.x * blockDim.x + threadIdx.x;
    if (f >= F) return;
    int i = faces[3 * f + 0];
    int j = faces[3 * f + 1];
    int k = faces[3 * f + 2];
    int ri = rank[3 * f + 0];
    int rj = rank[3 * f + 1];
    int rk = rank[3 * f + 2];
    long long* c2 = (long long*)col;
    __builtin_nontemporal_store(pack2(j, k), &c2[(off[i] + ri) >> 1]);
    __builtin_nontemporal_store(pack2(i, k), &c2[(off[j] + rj) >> 1]);
    __builtin_nontemporal_store(pack2(i, j), &c2[(off[k] + rk) >> 1]);
}

__device__ __forceinline__ void unpack_acc(uint2 r, float& ax, float& ay, float& az) {
    H2U xy, zw; xy.u = r.x; zw.u = r.y;
    float2 f0 = __half22float2(xy.h);
    float2 f1 = __half22float2(zw.h);
    ax += f0.x; ay += f0.y; az += f1.x;
}

// ---------------- gather + finalize: thread per (v,b), b in low 3 bits ----------------
// Lanes b=0..7 of one v read vh[s*8 + 0..7] = one fully-consumed 64B line per
// neighbor. col reads: packed CSR int2, broadcast across the 8 b-lanes.
__global__ void gather_kernel(const uint2* __restrict__ vh,
                              const int* __restrict__ cnt,
                              const int* __restrict__ off,
                              const int* __restrict__ col,
                              float* __restrict__ out, int N) {
    int t = blockIdx.x * blockDim.x + threadIdx.x;
    if (t >= N * BATCH) return;
    int v = t >> 3;
    int b = t & 7;

    int c = cnt[v];
    int start = off[v];              // even
    const int2* c2 = (const int2*)col;
    int e0 = start >> 1;
    int e1 = (start + c) >> 1;

    float ax = 0.f, ay = 0.f, az = 0.f;
    int e = e0;
    for (; e + 4 <= e1; e += 4) {    // 8 independent vh gathers in flight
        int2 s01 = c2[e];
        int2 s23 = c2[e + 1];
        int2 s45 = c2[e + 2];
        int2 s67 = c2[e + 3];
        uint2 r0 = vh[((size_t)s01.x << 3) + b];
        uint2 r1 = vh[((size_t)s01.y << 3) + b];
        uint2 r2 = vh[((size_t)s23.x << 3) + b];
        uint2 r3 = vh[((size_t)s23.y << 3) + b];
        uint2 r4 = vh[((size_t)s45.x << 3) + b];
        uint2 r5 = vh[((size_t)s45.y << 3) + b];
        uint2 r6 = vh[((size_t)s67.x << 3) + b];
        uint2 r7 = vh[((size_t)s67.y << 3) + b];
        unpack_acc(r0, ax, ay, az); unpack_acc(r1, ax, ay, az);
        unpack_acc(r2, ax, ay, az); unpack_acc(r3, ax, ay, az);
        unpack_acc(r4, ax, ay, az); unpack_acc(r5, ax, ay, az);
        unpack_acc(r6, ax, ay, az); unpack_acc(r7, ax, ay, az);
    }
    for (; e < e1; ++e) {
        int2 ss = c2[e];
        uint2 r0 = vh[((size_t)ss.x << 3) + b];
        uint2 r1 = vh[((size_t)ss.y << 3) + b];
        unpack_acc(r0, ax, ay, az);
        unpack_acc(r1, ax, ay, az);
    }

    float invd = 1.0f / fmaxf((float)c, 1.0f);
    float sx = 0.f, sy = 0.f, sz = 0.f;
    unpack_acc(vh[t], sx, sy, sz);   // self (t == v*8 + b)
    float l0 = ax * invd - sx;
    float l1 = ay * invd - sy;
    float l2 = az * invd - sz;
    __builtin_nontemporal_store(sqrtf(l0 * l0 + l1 * l1 + l2 * l2),
                                &out[(size_t)b * N + v]);
}

// ---------------- fp32 fallback pieces (tiny ws) ----------------

__global__ void count_only_kernel(const int* __restrict__ faces, int* __restrict__ cnt,
                                  int* __restrict__ rank, int F) {
    int f = blockIdx.x * blockDim.x + threadIdx.x;
    if (f >= F) return;
    rank[3 * f + 0] = atomicAdd(&cnt[faces[3 * f + 0]], 2);
    rank[3 * f + 1] = atomicAdd(&cnt[faces[3 * f + 1]], 2);
    rank[3 * f + 2] = atomicAdd(&cnt[faces[3 * f + 2]], 2);
}

__global__ void gather_scalar_kernel(const float* __restrict__ vert,
                                     const int* __restrict__ cnt,
                                     const int* __restrict__ off,
                                     const int* __restrict__ col,
                                     float* __restrict__ out, int N) {
    int v = blockIdx.x * blockDim.x + threadIdx.x;
    if (v >= N) return;
    int c = cnt[v];
    int start = off[v];
    int end = start + c;
    float ax[BATCH], ay[BATCH], az[BATCH];
    #pragma unroll
    for (int b = 0; b < BATCH; ++b) { ax[b] = 0.f; ay[b] = 0.f; az[b] = 0.f; }
    for (int e = start; e < end; ++e) {
        int s = col[e];
        #pragma unroll
        for (int b = 0; b < BATCH; ++b) {
            size_t base = ((size_t)b * N + s) * 3;
            ax[b] += vert[base + 0];
            ay[b] += vert[base + 1];
            az[b] += vert[base + 2];
        }
    }
    float invd = 1.0f / fmaxf((float)c, 1.0f);
    #pragma unroll
    for (int b = 0; b < BATCH; ++b) {
        size_t base = ((size_t)b * N + v) * 3;
        float l0 = ax[b] * invd - vert[base + 0];
        float l1 = ay[b] * invd - vert[base + 1];
        float l2 = az[b] * invd - vert[base + 2];
        out[(size_t)b * N + v] = sqrtf(l0 * l0 + l1 * l1 + l2 * l2);
    }
}

// ---------------- launch ----------------

static inline size_t align256(size_t x) { return (x + 255) & ~(size_t)255; }

extern "C" void kernel_launch(void* const* d_in, const int* in_sizes, int n_in,
                              void* d_out, int out_size, void* d_ws, size_t ws_size,
                              hipStream_t stream) {
    const float* vert  = (const float*)d_in[0];
    const int*   faces = (const int*)d_in[1];
    float*       out   = (float*)d_out;

    int N = out_size / BATCH;      // 500000
    int F = in_sizes[1] / 3;       // 1000000
    int E = 6 * F;

    char* ws = (char*)d_ws;
    int threads = 256;
    int nb = (N + SCAN_TILE - 1) / SCAN_TILE;   // 245 for N=500000

    // Layout: cnt[N] | off[N] | bsums[1024] | col[E] | vh[N*B] uint2 | rank[3F]
    size_t o_cnt   = 0;
    size_t o_off   = align256((size_t)N * 4);
    size_t o_bsums = o_off + align256((size_t)N * 4);
    size_t o_col   = o_bsums + 4096;
    size_t o_vh    = o_col + align256((size_t)E * 4);
    size_t o_rank  = o_vh + align256((size_t)N * BATCH * sizeof(uint2));
    size_t need    = o_rank + (size_t)3 * F * 4;

    int* cnt   = (int*)(ws + o_cnt);
    int* off   = (int*)(ws + o_off);
    int* bsums = (int*)(ws + o_bsums);
    int* col   = (int*)(ws + o_col);

    (void)hipMemsetAsync(cnt, 0, (size_t)N * 4, stream);

    if (ws_size >= need && nb <= SCAN_T) {
        uint2* vh  = (uint2*)(ws + o_vh);
        int*  rank = (int*)(ws + o_rank);

        int cntBlocks    = (F + threads - 1) / threads;
        int repackBlocks = (N * BATCH + threads - 1) / threads;
        count_repack_kernel<<<cntBlocks + repackBlocks, threads, 0, stream>>>(
            faces, cnt, rank, vert, vh, N, F, cntBlocks);

        scan_sums_kernel<<<nb, SCAN_T, 0, stream>>>(cnt, bsums, N);
        scan_apply_kernel<<<nb, SCAN_T, 0, stream>>>(cnt, off, bsums, N, nb);

        fill_kernel<<<cntBlocks, threads, 0, stream>>>(faces, off, rank, col, F);

        int total = N * BATCH;
        gather_kernel<<<(total + threads - 1) / threads, threads, 0, stream>>>(
            vh, cnt, off, col, out, N);
        return;
    }

    // ---- compact fp32 fallback: rank aliases the vh region ----
    int* rank = (int*)(ws + o_vh);
    int cntBlocks = (F + threads - 1) / threads;

    count_only_kernel<<<cntBlocks, threads, 0, stream>>>(faces, cnt, rank, F);
    scan_sums_kernel<<<nb, SCAN_T, 0, stream>>>(cnt, bsums, N);
    scan_apply_kernel<<<nb, SCAN_T, 0, stream>>>(cnt, off, bsums, N, nb);
    fill_kernel<<<cntBlocks, threads, 0, stream>>>(faces, off, rank, col, F);
    gather_scalar_kernel<<<(N + threads - 1) / threads, threads, 0, stream>>>(
        vert, cnt, off, col, out, N);
}

// Round 10
// 383.524 us; speedup vs baseline: 1.1355x; 1.1355x over previous
//
#include <hip/hip_runtime.h>
#include <hip/hip_fp16.h>
#include <math.h>

#define BATCH 8
#define SCAN_T 256
#define SCAN_E 8
#define SCAN_TILE (SCAN_T * SCAN_E)   // 2048 elems per scan block

union H2U { __half2 h; unsigned u; };

// ---------------- count + repack fused ----------------
// Blocks [0, cntBlocks): PURE atomic histogram (critical path, launched first).
//   cnt[v] += 2 per corner; rank[corner] = pre-add value (even), coalesced store.
// Remaining blocks: repack vert [B][N][3] fp32 -> vh [N][B] half4 (uint2, 8B).
// Repack streaming rides the memory pipe the atomic-latency-bound count waves
// leave idle (R7: fusion costs +20us on count but removes 30us from fill).
__global__ void count_repack_kernel(const int* __restrict__ faces,
                                    int* __restrict__ cnt,
                                    int* __restrict__ rank,
                                    const float* __restrict__ vert,
                                    uint2* __restrict__ vh,
                                    int N, int F, int cntBlocks) {
    if ((int)blockIdx.x < cntBlocks) {
        int f = blockIdx.x * blockDim.x + threadIdx.x;
        if (f >= F) return;
        int i = faces[3 * f + 0];
        int j = faces[3 * f + 1];
        int k = faces[3 * f + 2];
        rank[3 * f + 0] = atomicAdd(&cnt[i], 2);
        rank[3 * f + 1] = atomicAdd(&cnt[j], 2);
        rank[3 * f + 2] = atomicAdd(&cnt[k], 2);
    } else {
        int u = (blockIdx.x - cntBlocks) * blockDim.x + threadIdx.x;
        if (u >= N * BATCH) return;
        int v = u >> 3;
        int b = u & 7;
        size_t src = ((size_t)b * N + v) * 3;
        H2U xy, zw;
        xy.h = __floats2half2_rn(vert[src], vert[src + 1]);
        zw.h = __floats2half2_rn(vert[src + 2], 0.0f);
        uint2 w; w.x = xy.u; w.y = zw.u;
        vh[u] = w;   // u == v*8 + b
    }
}

// ---------------- scan: two parallel passes (R6-proven, ~25us total) ----------------
// R7's single-pass decoupled lookback was ~85us: 245 serially-dependent L2
// round-trips lose to two parallel 2MB passes at this N.
__global__ void scan_sums_kernel(const int* __restrict__ cnt, int* __restrict__ bsums, int N) {
    __shared__ int sh[SCAN_T];
    int base = blockIdx.x * SCAN_TILE + threadIdx.x * SCAN_E;
    int s = 0;
    #pragma unroll
    for (int e = 0; e < SCAN_E; ++e)
        if (base + e < N) s += cnt[base + e];
    sh[threadIdx.x] = s;
    __syncthreads();
    for (int d = SCAN_T / 2; d > 0; d >>= 1) {
        if (threadIdx.x < (unsigned)d) sh[threadIdx.x] += sh[threadIdx.x + d];
        __syncthreads();
    }
    if (threadIdx.x == 0) bsums[blockIdx.x] = sh[0];
}

__global__ void scan_apply_kernel(const int* __restrict__ cnt, int* __restrict__ off,
                                  const int* __restrict__ bsums, int N, int nb) {
    __shared__ int shb[SCAN_T];
    __shared__ int sh[SCAN_T];
    int bv = ((int)threadIdx.x < nb) ? bsums[threadIdx.x] : 0;
    shb[threadIdx.x] = bv;
    __syncthreads();
    for (int d = 1; d < SCAN_T; d <<= 1) {
        int t = (threadIdx.x >= (unsigned)d) ? shb[threadIdx.x - d] : 0;
        __syncthreads();
        shb[threadIdx.x] += t;
        __syncthreads();
    }
    int block_prefix = (blockIdx.x > 0) ? shb[blockIdx.x - 1] : 0;

    int base = blockIdx.x * SCAN_TILE + threadIdx.x * SCAN_E;
    int vals[SCAN_E];
    int s = 0;
    #pragma unroll
    for (int e = 0; e < SCAN_E; ++e) {
        int v = (base + e < N) ? cnt[base + e] : 0;
        vals[e] = v; s += v;
    }
    sh[threadIdx.x] = s;
    __syncthreads();
    for (int d = 1; d < SCAN_T; d <<= 1) {
        int t = (threadIdx.x >= (unsigned)d) ? sh[threadIdx.x - d] : 0;
        __syncthreads();
        sh[threadIdx.x] += t;
        __syncthreads();
    }
    int excl = block_prefix + ((threadIdx.x > 0) ? sh[threadIdx.x - 1] : 0);
    #pragma unroll
    for (int e = 0; e < SCAN_E; ++e) {
        if (base + e < N) off[base + e] = excl;
        excl += vals[e];
    }
}

// ---------------- pure fill (atomic-free; R4-proven; PLAIN stores) ----------------
// R9 post-mortem: non-temporal col stores bypassed L2 and cost ~60us — col is
// produced here and consumed by gather right after; it MUST stay L2-resident.
__global__ void fill_kernel(const int* __restrict__ faces, const int* __restrict__ off,
                            const int* __restrict__ rank, int* __restrict__ col, int F) {
    int f = blockIdx.x * blockDim.x + threadIdx.x;
    if (f >= F) return;
    int i = faces[3 * f + 0];
    int j = faces[3 * f + 1];
    int k = faces[3 * f + 2];
    int ri = rank[3 * f + 0];
    int rj = rank[3 * f + 1];
    int rk = rank[3 * f + 2];
    int2* c2 = (int2*)col;
    c2[(off[i] + ri) >> 1] = make_int2(j, k);
    c2[(off[j] + rj) >> 1] = make_int2(i, k);
    c2[(off[k] + rk) >> 1] = make_int2(i, j);
}

__device__ __forceinline__ void unpack_acc(uint2 r, float& ax, float& ay, float& az) {
    H2U xy, zw; xy.u = r.x; zw.u = r.y;
    float2 f0 = __half22float2(xy.h);
    float2 f1 = __half22float2(zw.h);
    ax += f0.x; ay += f0.y; az += f1.x;
}

// ---------------- gather + finalize: thread per (v,b), b in low 3 bits ----------------
// Lanes b=0..7 of one v read vh[s*8 + 0..7] = one fully-consumed 64B line per
// neighbor. col reads: packed CSR int2, broadcast across the 8 b-lanes.
__global__ void gather_kernel(const uint2* __restrict__ vh,
                              const int* __restrict__ cnt,
                              const int* __restrict__ off,
                              const int* __restrict__ col,
                              float* __restrict__ out, int N) {
    int t = blockIdx.x * blockDim.x + threadIdx.x;
    if (t >= N * BATCH) return;
    int v = t >> 3;
    int b = t & 7;

    int c = cnt[v];
    int start = off[v];              // even
    const int2* c2 = (const int2*)col;
    int e0 = start >> 1;
    int e1 = (start + c) >> 1;

    float ax = 0.f, ay = 0.f, az = 0.f;
    int e = e0;
    for (; e + 4 <= e1; e += 4) {    // 8 independent vh gathers in flight
        int2 s01 = c2[e];
        int2 s23 = c2[e + 1];
        int2 s45 = c2[e + 2];
        int2 s67 = c2[e + 3];
        uint2 r0 = vh[((size_t)s01.x << 3) + b];
        uint2 r1 = vh[((size_t)s01.y << 3) + b];
        uint2 r2 = vh[((size_t)s23.x << 3) + b];
        uint2 r3 = vh[((size_t)s23.y << 3) + b];
        uint2 r4 = vh[((size_t)s45.x << 3) + b];
        uint2 r5 = vh[((size_t)s45.y << 3) + b];
        uint2 r6 = vh[((size_t)s67.x << 3) + b];
        uint2 r7 = vh[((size_t)s67.y << 3) + b];
        unpack_acc(r0, ax, ay, az); unpack_acc(r1, ax, ay, az);
        unpack_acc(r2, ax, ay, az); unpack_acc(r3, ax, ay, az);
        unpack_acc(r4, ax, ay, az); unpack_acc(r5, ax, ay, az);
        unpack_acc(r6, ax, ay, az); unpack_acc(r7, ax, ay, az);
    }
    for (; e < e1; ++e) {
        int2 ss = c2[e];
        uint2 r0 = vh[((size_t)ss.x << 3) + b];
        uint2 r1 = vh[((size_t)ss.y << 3) + b];
        unpack_acc(r0, ax, ay, az);
        unpack_acc(r1, ax, ay, az);
    }

    float invd = 1.0f / fmaxf((float)c, 1.0f);
    float sx = 0.f, sy = 0.f, sz = 0.f;
    unpack_acc(vh[t], sx, sy, sz);   // self (t == v*8 + b)
    float l0 = ax * invd - sx;
    float l1 = ay * invd - sy;
    float l2 = az * invd - sz;
    out[(size_t)b * N + v] = sqrtf(l0 * l0 + l1 * l1 + l2 * l2);
}

// ---------------- fp32 fallback pieces (tiny ws) ----------------

__global__ void count_only_kernel(const int* __restrict__ faces, int* __restrict__ cnt,
                                  int* __restrict__ rank, int F) {
    int f = blockIdx.x * blockDim.x + threadIdx.x;
    if (f >= F) return;
    rank[3 * f + 0] = atomicAdd(&cnt[faces[3 * f + 0]], 2);
    rank[3 * f + 1] = atomicAdd(&cnt[faces[3 * f + 1]], 2);
    rank[3 * f + 2] = atomicAdd(&cnt[faces[3 * f + 2]], 2);
}

__global__ void gather_scalar_kernel(const float* __restrict__ vert,
                                     const int* __restrict__ cnt,
                                     const int* __restrict__ off,
                                     const int* __restrict__ col,
                                     float* __restrict__ out, int N) {
    int v = blockIdx.x * blockDim.x + threadIdx.x;
    if (v >= N) return;
    int c = cnt[v];
    int start = off[v];
    int end = start + c;
    float ax[BATCH], ay[BATCH], az[BATCH];
    #pragma unroll
    for (int b = 0; b < BATCH; ++b) { ax[b] = 0.f; ay[b] = 0.f; az[b] = 0.f; }
    for (int e = start; e < end; ++e) {
        int s = col[e];
        #pragma unroll
        for (int b = 0; b < BATCH; ++b) {
            size_t base = ((size_t)b * N + s) * 3;
            ax[b] += vert[base + 0];
            ay[b] += vert[base + 1];
            az[b] += vert[base + 2];
        }
    }
    float invd = 1.0f / fmaxf((float)c, 1.0f);
    #pragma unroll
    for (int b = 0; b < BATCH; ++b) {
        size_t base = ((size_t)b * N + v) * 3;
        float l0 = ax[b] * invd - vert[base + 0];
        float l1 = ay[b] * invd - vert[base + 1];
        float l2 = az[b] * invd - vert[base + 2];
        out[(size_t)b * N + v] = sqrtf(l0 * l0 + l1 * l1 + l2 * l2);
    }
}

// ---------------- launch ----------------

static inline size_t align256(size_t x) { return (x + 255) & ~(size_t)255; }

extern "C" void kernel_launch(void* const* d_in, const int* in_sizes, int n_in,
                              void* d_out, int out_size, void* d_ws, size_t ws_size,
                              hipStream_t stream) {
    const float* vert  = (const float*)d_in[0];
    const int*   faces = (const int*)d_in[1];
    float*       out   = (float*)d_out;

    int N = out_size / BATCH;      // 500000
    int F = in_sizes[1] / 3;       // 1000000
    int E = 6 * F;

    char* ws = (char*)d_ws;
    int threads = 256;
    int nb = (N + SCAN_TILE - 1) / SCAN_TILE;   // 245 for N=500000

    // Layout: cnt[N] | off[N] | bsums[1024] | col[E] | vh[N*B] uint2 | rank[3F]
    size_t o_cnt   = 0;
    size_t o_off   = align256((size_t)N * 4);
    size_t o_bsums = o_off + align256((size_t)N * 4);
    size_t o_col   = o_bsums + 4096;
    size_t o_vh    = o_col + align256((size_t)E * 4);
    size_t o_rank  = o_vh + align256((size_t)N * BATCH * sizeof(uint2));
    size_t need    = o_rank + (size_t)3 * F * 4;

    int* cnt   = (int*)(ws + o_cnt);
    int* off   = (int*)(ws + o_off);
    int* bsums = (int*)(ws + o_bsums);
    int* col   = (int*)(ws + o_col);

    (void)hipMemsetAsync(cnt, 0, (size_t)N * 4, stream);

    if (ws_size >= need && nb <= SCAN_T) {
        uint2* vh  = (uint2*)(ws + o_vh);
        int*  rank = (int*)(ws + o_rank);

        int cntBlocks    = (F + threads - 1) / threads;
        int repackBlocks = (N * BATCH + threads - 1) / threads;
        count_repack_kernel<<<cntBlocks + repackBlocks, threads, 0, stream>>>(
            faces, cnt, rank, vert, vh, N, F, cntBlocks);

        scan_sums_kernel<<<nb, SCAN_T, 0, stream>>>(cnt, bsums, N);
        scan_apply_kernel<<<nb, SCAN_T, 0, stream>>>(cnt, off, bsums, N, nb);

        fill_kernel<<<cntBlocks, threads, 0, stream>>>(faces, off, rank, col, F);

        int total = N * BATCH;
        gather_kernel<<<(total + threads - 1) / threads, threads, 0, stream>>>(
            vh, cnt, off, col, out, N);
        return;
    }

    // ---- compact fp32 fallback: rank aliases the vh region ----
    int* rank = (int*)(ws + o_vh);
    int cntBlocks = (F + threads - 1) / threads;

    count_only_kernel<<<cntBlocks, threads, 0, stream>>>(faces, cnt, rank, F);
    scan_sums_kernel<<<nb, SCAN_T, 0, stream>>>(cnt, bsums, N);
    scan_apply_kernel<<<nb, SCAN_T, 0, stream>>>(cnt, off, bsums, N, nb);
    fill_kernel<<<cntBlocks, threads, 0, stream>>>(faces, off, rank, col, F);
    gather_scalar_kernel<<<(N + threads - 1) / threads, threads, 0, stream>>>(
        vert, cnt, off, col, out, N);
}

// Round 11
// 246.420 us; speedup vs baseline: 1.7672x; 1.5564x over previous
//
#include <hip/hip_runtime.h>
#include <hip/hip_fp16.h>
#include <math.h>

#define BATCH 8
#define NBUK_MAX 512
#define BSHIFT 10                 // 1024 vertices per bucket
#define CAPB 6656                 // records/bucket capacity: mean 6135 (+6.7 sigma)
#define PACK_MASK 0x7FFFFull      // 19-bit fields (N <= 524288)
#define SCAN_T 256
#define SCAN_E 8
#define SCAN_TILE (SCAN_T * SCAN_E)

union H2U { __half2 h; unsigned u; };

// Record: corner at vertex v with neighbors a,b packed 19+19+19 bits into 8B.
__device__ __forceinline__ long long pack3(int v, int a, int b) {
    return (long long)(((unsigned long long)(unsigned)v) |
                       ((unsigned long long)(unsigned)a << 19) |
                       ((unsigned long long)(unsigned)b << 38));
}

// ---------------- K1: expand (bucketed, coalesced) + repack fused ----------------
// Expand blocks: LDS-bin 3072 corner-records by bucket, reserve space with ONE
// padded global atomic per touched bucket (~489/block vs 3072 scattered before),
// stage sorted in LDS, write coalesced runs. Kills the 3M-global-atomic floor.
// Repack blocks: vert [B][N][3] fp32 -> vh [N][B] half4 (proven R7/R10 rider).
__global__ __launch_bounds__(1024) void expand_repack_kernel(
        const int* __restrict__ faces,
        int* __restrict__ cursor,          // [NBUK_MAX*16] (64B-padded counters)
        long long* __restrict__ recbuf,    // [NB][CAPB]
        const float* __restrict__ vert,
        uint2* __restrict__ vh,
        int N, int F, int expBlocks) {
    if ((int)blockIdx.x < expBlocks) {
        __shared__ int hist[NBUK_MAX];
        __shared__ int sbuf[NBUK_MAX];
        __shared__ int lbase[NBUK_MAX];
        __shared__ int gb[NBUK_MAX];
        __shared__ long long stage[3072];
        int tid = threadIdx.x;
        for (int x = tid; x < NBUK_MAX; x += 1024) hist[x] = 0;
        __syncthreads();

        int f = blockIdx.x * 1024 + tid;
        bool valid = f < F;
        int bb0 = 0, bb1 = 0, bb2 = 0, rr0 = 0, rr1 = 0, rr2 = 0;
        long long rc0 = 0, rc1 = 0, rc2 = 0;
        if (valid) {
            int i = faces[3 * f + 0];
            int j = faces[3 * f + 1];
            int k = faces[3 * f + 2];
            rc0 = pack3(i, j, k);
            rc1 = pack3(j, i, k);
            rc2 = pack3(k, i, j);
            bb0 = i >> BSHIFT; bb1 = j >> BSHIFT; bb2 = k >> BSHIFT;
            rr0 = atomicAdd(&hist[bb0], 1);
            rr1 = atomicAdd(&hist[bb1], 1);
            rr2 = atomicAdd(&hist[bb2], 1);
        }
        __syncthreads();

        // inclusive scan of hist -> sbuf
        if (tid < NBUK_MAX) sbuf[tid] = hist[tid];
        __syncthreads();
        for (int d = 1; d < NBUK_MAX; d <<= 1) {
            int t = 0;
            if (tid < NBUK_MAX && tid >= d) t = sbuf[tid - d];
            __syncthreads();
            if (tid < NBUK_MAX) sbuf[tid] += t;
            __syncthreads();
        }
        if (tid < NBUK_MAX) {
            lbase[tid] = sbuf[tid] - hist[tid];
            gb[tid] = (hist[tid] > 0) ? atomicAdd(&cursor[tid * 16], hist[tid]) : 0;
        }
        __syncthreads();

        if (valid) {
            stage[lbase[bb0] + rr0] = rc0;
            stage[lbase[bb1] + rr1] = rc1;
            stage[lbase[bb2] + rr2] = rc2;
        }
        __syncthreads();

        int total = sbuf[NBUK_MAX - 1];
        for (int t = tid; t < total; t += 1024) {
            long long r = stage[t];
            int v = (int)((unsigned long long)r & PACK_MASK);
            int b = v >> BSHIFT;
            int gpos = gb[b] + (t - lbase[b]);
            if (gpos < CAPB)                       // overflow guard (+6.7 sigma)
                recbuf[(size_t)b * CAPB + gpos] = r;
        }
    } else {
        int u = (blockIdx.x - expBlocks) * 1024 + threadIdx.x;
        if (u < N * BATCH) {
            int v = u >> 3;
            int b = u & 7;
            size_t src = ((size_t)b * N + v) * 3;
            H2U xy, zw;
            xy.h = __floats2half2_rn(vert[src], vert[src + 1]);
            zw.h = __floats2half2_rn(vert[src + 2], 0.0f);
            uint2 w; w.x = xy.u; w.y = zw.u;
            vh[u] = w;   // u == v*8 + b
        }
    }
}

// ---------------- K2: per-bucket CSR build, all-coalesced global I/O ----------------
// One block per bucket (1024 vertices, ~6.1K records). LDS histogram -> cnt,
// LDS scan -> off, col assembled in LDS colbuf then flushed coalesced.
// Kills the 3M-scattered-8B-store floor (old fill: ~85us).
__global__ __launch_bounds__(1024) void bucket_build_kernel(
        const int* __restrict__ cursor,
        const long long* __restrict__ recbuf,
        int* __restrict__ cnt, int* __restrict__ off, int* __restrict__ col,
        int N, int NB) {
    __shared__ int cu[NBUK_MAX];
    __shared__ int cntL[1024];
    __shared__ int2 colbuf[CAPB];       // 52 KB
    int tid = threadIdx.x;
    int bid = blockIdx.x;

    if (tid < NBUK_MAX) {
        int c = (tid < NB) ? cursor[tid * 16] : 0;
        cu[tid] = c < CAPB ? c : CAPB;   // clamp matches stored records
    }
    __syncthreads();
    for (int d = 1; d < NBUK_MAX; d <<= 1) {
        int t = 0;
        if (tid < NBUK_MAX && tid >= d) t = cu[tid - d];
        __syncthreads();
        if (tid < NBUK_MAX) cu[tid] += t;
        __syncthreads();
    }
    int excl = (bid > 0) ? cu[bid - 1] : 0;
    int rcnt = cu[bid] - excl;
    int base_edge = excl * 2;
    int v0 = bid << BSHIFT;
    int nv = N - v0; if (nv > 1024) nv = 1024;

    cntL[tid] = 0;
    __syncthreads();
    const long long* recs = recbuf + (size_t)bid * CAPB;
    for (int x = tid; x < rcnt; x += 1024) {
        int v = (int)((unsigned long long)recs[x] & PACK_MASK);
        atomicAdd(&cntL[v & 1023], 2);
    }
    __syncthreads();

    int myc = cntL[tid];
    if (tid < nv) cnt[v0 + tid] = myc;           // deg (coalesced)
    // inclusive scan cntL in place
    for (int d = 1; d < 1024; d <<= 1) {
        int t = (tid >= d) ? cntL[tid - d] : 0;
        __syncthreads();
        cntL[tid] += t;
        __syncthreads();
    }
    int myoff = cntL[tid] - myc;                 // exclusive, edge units
    __syncthreads();
    cntL[tid] = myoff;                           // cntL becomes running cursor
    if (tid < nv) off[v0 + tid] = base_edge + myoff;   // coalesced
    __syncthreads();

    for (int x = tid; x < rcnt; x += 1024) {
        unsigned long long r = (unsigned long long)recs[x];
        int v = (int)(r & PACK_MASK);
        int a = (int)((r >> 19) & PACK_MASK);
        int b = (int)((r >> 38) & PACK_MASK);
        int p = atomicAdd(&cntL[v & 1023], 2);   // LDS scatter, not global
        colbuf[p >> 1] = make_int2(a, b);
    }
    __syncthreads();
    int2* c2 = (int2*)col;
    int base2 = base_edge >> 1;
    for (int x = tid; x < rcnt; x += 1024)       // coalesced flush
        c2[base2 + x] = colbuf[x];
}

__device__ __forceinline__ void unpack_acc(uint2 r, float& ax, float& ay, float& az) {
    H2U xy, zw; xy.u = r.x; zw.u = r.y;
    float2 f0 = __half22float2(xy.h);
    float2 f1 = __half22float2(zw.h);
    ax += f0.x; ay += f0.y; az += f1.x;
}

// ---------------- gather + finalize (unchanged from R10, proven ~95us) ----------------
__global__ void gather_kernel(const uint2* __restrict__ vh,
                              const int* __restrict__ cnt,
                              const int* __restrict__ off,
                              const int* __restrict__ col,
                              float* __restrict__ out, int N) {
    int t = blockIdx.x * blockDim.x + threadIdx.x;
    if (t >= N * BATCH) return;
    int v = t >> 3;
    int b = t & 7;

    int c = cnt[v];
    int start = off[v];              // even
    const int2* c2 = (const int2*)col;
    int e0 = start >> 1;
    int e1 = (start + c) >> 1;

    float ax = 0.f, ay = 0.f, az = 0.f;
    int e = e0;
    for (; e + 4 <= e1; e += 4) {    // 8 independent vh gathers in flight
        int2 s01 = c2[e];
        int2 s23 = c2[e + 1];
        int2 s45 = c2[e + 2];
        int2 s67 = c2[e + 3];
        uint2 r0 = vh[((size_t)s01.x << 3) + b];
        uint2 r1 = vh[((size_t)s01.y << 3) + b];
        uint2 r2 = vh[((size_t)s23.x << 3) + b];
        uint2 r3 = vh[((size_t)s23.y << 3) + b];
        uint2 r4 = vh[((size_t)s45.x << 3) + b];
        uint2 r5 = vh[((size_t)s45.y << 3) + b];
        uint2 r6 = vh[((size_t)s67.x << 3) + b];
        uint2 r7 = vh[((size_t)s67.y << 3) + b];
        unpack_acc(r0, ax, ay, az); unpack_acc(r1, ax, ay, az);
        unpack_acc(r2, ax, ay, az); unpack_acc(r3, ax, ay, az);
        unpack_acc(r4, ax, ay, az); unpack_acc(r5, ax, ay, az);
        unpack_acc(r6, ax, ay, az); unpack_acc(r7, ax, ay, az);
    }
    for (; e < e1; ++e) {
        int2 ss = c2[e];
        uint2 r0 = vh[((size_t)ss.x << 3) + b];
        uint2 r1 = vh[((size_t)ss.y << 3) + b];
        unpack_acc(r0, ax, ay, az);
        unpack_acc(r1, ax, ay, az);
    }

    float invd = 1.0f / fmaxf((float)c, 1.0f);
    float sx = 0.f, sy = 0.f, sz = 0.f;
    unpack_acc(vh[t], sx, sy, sz);   // self (t == v*8 + b)
    float l0 = ax * invd - sx;
    float l1 = ay * invd - sy;
    float l2 = az * invd - sz;
    out[(size_t)b * N + v] = sqrtf(l0 * l0 + l1 * l1 + l2 * l2);
}

// ---------------- fp32 fallback (tiny ws / oversized N) ----------------

__global__ void count_only_kernel(const int* __restrict__ faces, int* __restrict__ cnt,
                                  int* __restrict__ rank, int F) {
    int f = blockIdx.x * blockDim.x + threadIdx.x;
    if (f >= F) return;
    rank[3 * f + 0] = atomicAdd(&cnt[faces[3 * f + 0]], 2);
    rank[3 * f + 1] = atomicAdd(&cnt[faces[3 * f + 1]], 2);
    rank[3 * f + 2] = atomicAdd(&cnt[faces[3 * f + 2]], 2);
}

__global__ void scan_sums_kernel(const int* __restrict__ cnt, int* __restrict__ bsums, int N) {
    __shared__ int sh[SCAN_T];
    int base = blockIdx.x * SCAN_TILE + threadIdx.x * SCAN_E;
    int s = 0;
    #pragma unroll
    for (int e = 0; e < SCAN_E; ++e)
        if (base + e < N) s += cnt[base + e];
    sh[threadIdx.x] = s;
    __syncthreads();
    for (int d = SCAN_T / 2; d > 0; d >>= 1) {
        if (threadIdx.x < (unsigned)d) sh[threadIdx.x] += sh[threadIdx.x + d];
        __syncthreads();
    }
    if (threadIdx.x == 0) bsums[blockIdx.x] = sh[0];
}

__global__ void scan_apply_kernel(const int* __restrict__ cnt, int* __restrict__ off,
                                  const int* __restrict__ bsums, int N, int nb) {
    __shared__ int shb[SCAN_T];
    __shared__ int sh[SCAN_T];
    int bv = ((int)threadIdx.x < nb) ? bsums[threadIdx.x] : 0;
    shb[threadIdx.x] = bv;
    __syncthreads();
    for (int d = 1; d < SCAN_T; d <<= 1) {
        int t = (threadIdx.x >= (unsigned)d) ? shb[threadIdx.x - d] : 0;
        __syncthreads();
        shb[threadIdx.x] += t;
        __syncthreads();
    }
    int block_prefix = (blockIdx.x > 0) ? shb[blockIdx.x - 1] : 0;

    int base = blockIdx.x * SCAN_TILE + threadIdx.x * SCAN_E;
    int vals[SCAN_E];
    int s = 0;
    #pragma unroll
    for (int e = 0; e < SCAN_E; ++e) {
        int v = (base + e < N) ? cnt[base + e] : 0;
        vals[e] = v; s += v;
    }
    sh[threadIdx.x] = s;
    __syncthreads();
    for (int d = 1; d < SCAN_T; d <<= 1) {
        int t = (threadIdx.x >= (unsigned)d) ? sh[threadIdx.x - d] : 0;
        __syncthreads();
        sh[threadIdx.x] += t;
        __syncthreads();
    }
    int excl = block_prefix + ((threadIdx.x > 0) ? sh[threadIdx.x - 1] : 0);
    #pragma unroll
    for (int e = 0; e < SCAN_E; ++e) {
        if (base + e < N) off[base + e] = excl;
        excl += vals[e];
    }
}

__global__ void fill_kernel(const int* __restrict__ faces, const int* __restrict__ off,
                            const int* __restrict__ rank, int* __restrict__ col, int F) {
    int f = blockIdx.x * blockDim.x + threadIdx.x;
    if (f >= F) return;
    int i = faces[3 * f + 0];
    int j = faces[3 * f + 1];
    int k = faces[3 * f + 2];
    int2* c2 = (int2*)col;
    c2[(off[i] + rank[3 * f + 0]) >> 1] = make_int2(j, k);
    c2[(off[j] + rank[3 * f + 1]) >> 1] = make_int2(i, k);
    c2[(off[k] + rank[3 * f + 2]) >> 1] = make_int2(i, j);
}

__global__ void gather_scalar_kernel(const float* __restrict__ vert,
                                     const int* __restrict__ cnt,
                                     const int* __restrict__ off,
                                     const int* __restrict__ col,
                                     float* __restrict__ out, int N) {
    int v = blockIdx.x * blockDim.x + threadIdx.x;
    if (v >= N) return;
    int c = cnt[v];
    int start = off[v];
    int end = start + c;
    float ax[BATCH], ay[BATCH], az[BATCH];
    #pragma unroll
    for (int b = 0; b < BATCH; ++b) { ax[b] = 0.f; ay[b] = 0.f; az[b] = 0.f; }
    for (int e = start; e < end; ++e) {
        int s = col[e];
        #pragma unroll
        for (int b = 0; b < BATCH; ++b) {
            size_t base = ((size_t)b * N + s) * 3;
            ax[b] += vert[base + 0];
            ay[b] += vert[base + 1];
            az[b] += vert[base + 2];
        }
    }
    float invd = 1.0f / fmaxf((float)c, 1.0f);
    #pragma unroll
    for (int b = 0; b < BATCH; ++b) {
        size_t base = ((size_t)b * N + v) * 3;
        float l0 = ax[b] * invd - vert[base + 0];
        float l1 = ay[b] * invd - vert[base + 1];
        float l2 = az[b] * invd - vert[base + 2];
        out[(size_t)b * N + v] = sqrtf(l0 * l0 + l1 * l1 + l2 * l2);
    }
}

// ---------------- launch ----------------

static inline size_t align256(size_t x) { return (x + 255) & ~(size_t)255; }

extern "C" void kernel_launch(void* const* d_in, const int* in_sizes, int n_in,
                              void* d_out, int out_size, void* d_ws, size_t ws_size,
                              hipStream_t stream) {
    const float* vert  = (const float*)d_in[0];
    const int*   faces = (const int*)d_in[1];
    float*       out   = (float*)d_out;

    int N = out_size / BATCH;      // 500000
    int F = in_sizes[1] / 3;       // 1000000
    int E = 6 * F;
    int NB = (N + (1 << BSHIFT) - 1) >> BSHIFT;   // 489 buckets

    char* ws = (char*)d_ws;

    // New layout: cursor(32KB) | cnt[N] | off[N] | col[E] | vh[N*B] uint2 | rec[NB*CAPB] i64
    size_t o_cursor = 0;
    size_t o_cnt    = NBUK_MAX * 64;
    size_t o_off    = o_cnt + align256((size_t)N * 4);
    size_t o_col    = o_off + align256((size_t)N * 4);
    size_t o_vh     = o_col + align256((size_t)E * 4);
    size_t o_rec    = o_vh + align256((size_t)N * BATCH * sizeof(uint2));
    size_t need     = o_rec + (size_t)NB * CAPB * 8;

    if (ws_size >= need && N <= 524288 && NB <= NBUK_MAX) {
        int*       cursor = (int*)(ws + o_cursor);
        int*       cnt    = (int*)(ws + o_cnt);
        int*       off    = (int*)(ws + o_off);
        int*       col    = (int*)(ws + o_col);
        uint2*     vh     = (uint2*)(ws + o_vh);
        long long* rec    = (long long*)(ws + o_rec);

        (void)hipMemsetAsync(cursor, 0, NBUK_MAX * 64, stream);

        int expB = (F + 1023) / 1024;
        int repB = (N * BATCH + 1023) / 1024;
        expand_repack_kernel<<<expB + repB, 1024, 0, stream>>>(
            faces, cursor, rec, vert, vh, N, F, expB);

        bucket_build_kernel<<<NB, 1024, 0, stream>>>(cursor, rec, cnt, off, col, N, NB);

        int total = N * BATCH;
        gather_kernel<<<(total + 255) / 256, 256, 0, stream>>>(vh, cnt, off, col, out, N);
        return;
    }

    // ---- compact fp32 fallback (R10-proven correctness path) ----
    int threads = 256;
    int nb = (N + SCAN_TILE - 1) / SCAN_TILE;
    size_t f_cnt   = 0;
    size_t f_off   = align256((size_t)N * 4);
    size_t f_bsums = f_off + align256((size_t)N * 4);
    size_t f_col   = f_bsums + 4096;
    size_t f_rank  = f_col + align256((size_t)E * 4);

    int* cnt   = (int*)(ws + f_cnt);
    int* off   = (int*)(ws + f_off);
    int* bsums = (int*)(ws + f_bsums);
    int* col   = (int*)(ws + f_col);
    int* rank  = (int*)(ws + f_rank);

    (void)hipMemsetAsync(cnt, 0, (size_t)N * 4, stream);

    int cntBlocks = (F + threads - 1) / threads;
    count_only_kernel<<<cntBlocks, threads, 0, stream>>>(faces, cnt, rank, F);
    scan_sums_kernel<<<nb, SCAN_T, 0, stream>>>(cnt, bsums, N);
    scan_apply_kernel<<<nb, SCAN_T, 0, stream>>>(cnt, off, bsums, N, nb);
    fill_kernel<<<cntBlocks, threads, 0, stream>>>(faces, off, rank, col, F);
    gather_scalar_kernel<<<(N + threads - 1) / threads, threads, 0, stream>>>(
        vert, cnt, off, col, out, N);
}

// Round 12
// 236.023 us; speedup vs baseline: 1.8450x; 1.0441x over previous
//
#include <hip/hip_runtime.h>
#include <hip/hip_fp16.h>
#include <math.h>

#define BATCH 8
#define NBUK_MAX 512
#define BSHIFT 10                 // 1024 vertices per bucket
#define CAPB 6656                 // records/bucket: mean 6144, +6.5 sigma, guarded
#define PACK_MASK 0x7FFFFull      // 19-bit fields (N <= 524288)
#define SCAN_T 256
#define SCAN_E 8
#define SCAN_TILE (SCAN_T * SCAN_E)

union H2U { __half2 h; unsigned u; };

__device__ __forceinline__ long long pack3(int v, int a, int b) {
    return (long long)(((unsigned long long)(unsigned)v) |
                       ((unsigned long long)(unsigned)a << 19) |
                       ((unsigned long long)(unsigned)b << 38));
}

// ---------------- K1: expand (bucketed, coalesced) + repack fused (R11-proven) --------
__global__ __launch_bounds__(1024) void expand_repack_kernel(
        const int* __restrict__ faces,
        int* __restrict__ cursor,          // [NBUK_MAX*16] (64B-padded counters)
        long long* __restrict__ recbuf,    // [NB][CAPB]
        const float* __restrict__ vert,
        uint2* __restrict__ vh,
        int N, int F, int expBlocks) {
    if ((int)blockIdx.x < expBlocks) {
        __shared__ int hist[NBUK_MAX];
        __shared__ int sbuf[NBUK_MAX];
        __shared__ int lbase[NBUK_MAX];
        __shared__ int gb[NBUK_MAX];
        __shared__ long long stage[3072];
        int tid = threadIdx.x;
        for (int x = tid; x < NBUK_MAX; x += 1024) hist[x] = 0;
        __syncthreads();

        int f = blockIdx.x * 1024 + tid;
        bool valid = f < F;
        int bb0 = 0, bb1 = 0, bb2 = 0, rr0 = 0, rr1 = 0, rr2 = 0;
        long long rc0 = 0, rc1 = 0, rc2 = 0;
        if (valid) {
            int i = faces[3 * f + 0];
            int j = faces[3 * f + 1];
            int k = faces[3 * f + 2];
            rc0 = pack3(i, j, k);
            rc1 = pack3(j, i, k);
            rc2 = pack3(k, i, j);
            bb0 = i >> BSHIFT; bb1 = j >> BSHIFT; bb2 = k >> BSHIFT;
            rr0 = atomicAdd(&hist[bb0], 1);
            rr1 = atomicAdd(&hist[bb1], 1);
            rr2 = atomicAdd(&hist[bb2], 1);
        }
        __syncthreads();

        if (tid < NBUK_MAX) sbuf[tid] = hist[tid];
        __syncthreads();
        for (int d = 1; d < NBUK_MAX; d <<= 1) {
            int t = 0;
            if (tid < NBUK_MAX && tid >= d) t = sbuf[tid - d];
            __syncthreads();
            if (tid < NBUK_MAX) sbuf[tid] += t;
            __syncthreads();
        }
        if (tid < NBUK_MAX) {
            lbase[tid] = sbuf[tid] - hist[tid];
            gb[tid] = (hist[tid] > 0) ? atomicAdd(&cursor[tid * 16], hist[tid]) : 0;
        }
        __syncthreads();

        if (valid) {
            stage[lbase[bb0] + rr0] = rc0;
            stage[lbase[bb1] + rr1] = rc1;
            stage[lbase[bb2] + rr2] = rc2;
        }
        __syncthreads();

        int total = sbuf[NBUK_MAX - 1];
        for (int t = tid; t < total; t += 1024) {
            long long r = stage[t];
            int v = (int)((unsigned long long)r & PACK_MASK);
            int b = v >> BSHIFT;
            int gpos = gb[b] + (t - lbase[b]);
            if (gpos < CAPB)
                recbuf[(size_t)b * CAPB + gpos] = r;
        }
    } else {
        int u = (blockIdx.x - expBlocks) * 1024 + threadIdx.x;
        if (u < N * BATCH) {
            int v = u >> 3;
            int b = u & 7;
            size_t src = ((size_t)b * N + v) * 3;
            H2U xy, zw;
            xy.h = __floats2half2_rn(vert[src], vert[src + 1]);
            zw.h = __floats2half2_rn(vert[src + 2], 0.0f);
            uint2 w; w.x = xy.u; w.y = zw.u;
            vh[u] = w;   // u == v*8 + b
        }
    }
}

__device__ __forceinline__ void unpack_acc(uint2 r, float& ax, float& ay, float& az) {
    H2U xy, zw; xy.u = r.x; zw.u = r.y;
    float2 f0 = __half22float2(xy.h);
    float2 f1 = __half22float2(zw.h);
    ax += f0.x; ay += f0.y; az += f1.x;
}

// ---------------- K2: per-bucket CSR build in LDS + FUSED gather ----------------
// The global CSR (col/cnt/off, 28MB written + 28MB read in R11) never leaves LDS.
// Build phase: hist -> scan -> LDS scatter into colbuf. Gather phase: 8 (v,b)
// pairs per thread, col entries via LDS broadcast, vh random 64B-line loads.
__global__ __launch_bounds__(1024) void bucket_gather_kernel(
        const int* __restrict__ cursor,
        const long long* __restrict__ recbuf,
        const uint2* __restrict__ vh,
        float* __restrict__ out, int N) {
    __shared__ int cntL[1024];          // hist -> inclusive scan -> running cursor (=end)
    __shared__ int offL[1024];          // exclusive offsets
    __shared__ int2 colbuf[CAPB];       // 52 KB; total LDS ~60 KB -> 2 blocks/CU
    int tid = threadIdx.x;
    int bid = blockIdx.x;
    int v0 = bid << BSHIFT;

    int rc = cursor[bid * 16];
    int rcnt = rc < CAPB ? rc : CAPB;   // overflow guard matches K1's stored records

    cntL[tid] = 0;
    __syncthreads();
    const long long* recs = recbuf + (size_t)bid * CAPB;
    for (int x = tid; x < rcnt; x += 1024) {
        int v = (int)((unsigned long long)recs[x] & PACK_MASK);
        atomicAdd(&cntL[v & 1023], 2);
    }
    __syncthreads();

    int myc = cntL[tid];
    for (int d = 1; d < 1024; d <<= 1) {        // inclusive scan
        int t = (tid >= d) ? cntL[tid - d] : 0;
        __syncthreads();
        cntL[tid] += t;
        __syncthreads();
    }
    int myoff = cntL[tid] - myc;
    cntL[tid] = myoff;                          // own-slot rewrite, no cross-read yet
    offL[tid] = myoff;
    __syncthreads();

    for (int x = tid; x < rcnt; x += 1024) {
        unsigned long long r = (unsigned long long)recs[x];
        int v = (int)(r & PACK_MASK);
        int a = (int)((r >> 19) & PACK_MASK);
        int b = (int)((r >> 38) & PACK_MASK);
        int p = atomicAdd(&cntL[v & 1023], 2);  // LDS scatter, not global
        colbuf[p >> 1] = make_int2(a, b);
    }
    __syncthreads();                            // cntL[lv] now == off+cnt (end)

    // ---- gather phase: thread handles (v = v0 + (tid>>3) + 128*it, b = tid&7) ----
    int b = tid & 7;
    for (int it = 0; it < (1 << BSHIFT) / 128; ++it) {
        int lv = (tid >> 3) + 128 * it;
        int v = v0 + lv;
        if (v >= N) continue;
        int start = offL[lv];                   // 8-lane LDS broadcast
        int end = cntL[lv];
        int c = end - start;
        int e = start >> 1, e1 = end >> 1;

        float ax = 0.f, ay = 0.f, az = 0.f;
        for (; e + 4 <= e1; e += 4) {           // 8 independent vh gathers in flight
            int2 s01 = colbuf[e];
            int2 s23 = colbuf[e + 1];
            int2 s45 = colbuf[e + 2];
            int2 s67 = colbuf[e + 3];
            uint2 r0 = vh[((size_t)s01.x << 3) + b];
            uint2 r1 = vh[((size_t)s01.y << 3) + b];
            uint2 r2 = vh[((size_t)s23.x << 3) + b];
            uint2 r3 = vh[((size_t)s23.y << 3) + b];
            uint2 r4 = vh[((size_t)s45.x << 3) + b];
            uint2 r5 = vh[((size_t)s45.y << 3) + b];
            uint2 r6 = vh[((size_t)s67.x << 3) + b];
            uint2 r7 = vh[((size_t)s67.y << 3) + b];
            unpack_acc(r0, ax, ay, az); unpack_acc(r1, ax, ay, az);
            unpack_acc(r2, ax, ay, az); unpack_acc(r3, ax, ay, az);
            unpack_acc(r4, ax, ay, az); unpack_acc(r5, ax, ay, az);
            unpack_acc(r6, ax, ay, az); unpack_acc(r7, ax, ay, az);
        }
        for (; e < e1; ++e) {
            int2 ss = colbuf[e];
            uint2 r0 = vh[((size_t)ss.x << 3) + b];
            uint2 r1 = vh[((size_t)ss.y << 3) + b];
            unpack_acc(r0, ax, ay, az);
            unpack_acc(r1, ax, ay, az);
        }

        float invd = 1.0f / fmaxf((float)c, 1.0f);
        float sx = 0.f, sy = 0.f, sz = 0.f;
        unpack_acc(vh[((size_t)v << 3) + b], sx, sy, sz);
        float l0 = ax * invd - sx;
        float l1 = ay * invd - sy;
        float l2 = az * invd - sz;
        out[(size_t)b * N + v] = sqrtf(l0 * l0 + l1 * l1 + l2 * l2);
    }
}

// ---------------- fp32 fallback (tiny ws / oversized N) — R10-proven ----------------

__global__ void count_only_kernel(const int* __restrict__ faces, int* __restrict__ cnt,
                                  int* __restrict__ rank, int F) {
    int f = blockIdx.x * blockDim.x + threadIdx.x;
    if (f >= F) return;
    rank[3 * f + 0] = atomicAdd(&cnt[faces[3 * f + 0]], 2);
    rank[3 * f + 1] = atomicAdd(&cnt[faces[3 * f + 1]], 2);
    rank[3 * f + 2] = atomicAdd(&cnt[faces[3 * f + 2]], 2);
}

__global__ void scan_sums_kernel(const int* __restrict__ cnt, int* __restrict__ bsums, int N) {
    __shared__ int sh[SCAN_T];
    int base = blockIdx.x * SCAN_TILE + threadIdx.x * SCAN_E;
    int s = 0;
    #pragma unroll
    for (int e = 0; e < SCAN_E; ++e)
        if (base + e < N) s += cnt[base + e];
    sh[threadIdx.x] = s;
    __syncthreads();
    for (int d = SCAN_T / 2; d > 0; d >>= 1) {
        if (threadIdx.x < (unsigned)d) sh[threadIdx.x] += sh[threadIdx.x + d];
        __syncthreads();
    }
    if (threadIdx.x == 0) bsums[blockIdx.x] = sh[0];
}

__global__ void scan_apply_kernel(const int* __restrict__ cnt, int* __restrict__ off,
                                  const int* __restrict__ bsums, int N, int nb) {
    __shared__ int shb[SCAN_T];
    __shared__ int sh[SCAN_T];
    int bv = ((int)threadIdx.x < nb) ? bsums[threadIdx.x] : 0;
    shb[threadIdx.x] = bv;
    __syncthreads();
    for (int d = 1; d < SCAN_T; d <<= 1) {
        int t = (threadIdx.x >= (unsigned)d) ? shb[threadIdx.x - d] : 0;
        __syncthreads();
        shb[threadIdx.x] += t;
        __syncthreads();
    }
    int block_prefix = (blockIdx.x > 0) ? shb[blockIdx.x - 1] : 0;

    int base = blockIdx.x * SCAN_TILE + threadIdx.x * SCAN_E;
    int vals[SCAN_E];
    int s = 0;
    #pragma unroll
    for (int e = 0; e < SCAN_E; ++e) {
        int v = (base + e < N) ? cnt[base + e] : 0;
        vals[e] = v; s += v;
    }
    sh[threadIdx.x] = s;
    __syncthreads();
    for (int d = 1; d < SCAN_T; d <<= 1) {
        int t = (threadIdx.x >= (unsigned)d) ? sh[threadIdx.x - d] : 0;
        __syncthreads();
        sh[threadIdx.x] += t;
        __syncthreads();
    }
    int excl = block_prefix + ((threadIdx.x > 0) ? sh[threadIdx.x - 1] : 0);
    #pragma unroll
    for (int e = 0; e < SCAN_E; ++e) {
        if (base + e < N) off[base + e] = excl;
        excl += vals[e];
    }
}

__global__ void fill_kernel(const int* __restrict__ faces, const int* __restrict__ off,
                            const int* __restrict__ rank, int* __restrict__ col, int F) {
    int f = blockIdx.x * blockDim.x + threadIdx.x;
    if (f >= F) return;
    int i = faces[3 * f + 0];
    int j = faces[3 * f + 1];
    int k = faces[3 * f + 2];
    int2* c2 = (int2*)col;
    c2[(off[i] + rank[3 * f + 0]) >> 1] = make_int2(j, k);
    c2[(off[j] + rank[3 * f + 1]) >> 1] = make_int2(i, k);
    c2[(off[k] + rank[3 * f + 2]) >> 1] = make_int2(i, j);
}

__global__ void gather_scalar_kernel(const float* __restrict__ vert,
                                     const int* __restrict__ cnt,
                                     const int* __restrict__ off,
                                     const int* __restrict__ col,
                                     float* __restrict__ out, int N) {
    int v = blockIdx.x * blockDim.x + threadIdx.x;
    if (v >= N) return;
    int c = cnt[v];
    int start = off[v];
    int end = start + c;
    float ax[BATCH], ay[BATCH], az[BATCH];
    #pragma unroll
    for (int b = 0; b < BATCH; ++b) { ax[b] = 0.f; ay[b] = 0.f; az[b] = 0.f; }
    for (int e = start; e < end; ++e) {
        int s = col[e];
        #pragma unroll
        for (int b = 0; b < BATCH; ++b) {
            size_t base = ((size_t)b * N + s) * 3;
            ax[b] += vert[base + 0];
            ay[b] += vert[base + 1];
            az[b] += vert[base + 2];
        }
    }
    float invd = 1.0f / fmaxf((float)c, 1.0f);
    #pragma unroll
    for (int b = 0; b < BATCH; ++b) {
        size_t base = ((size_t)b * N + v) * 3;
        float l0 = ax[b] * invd - vert[base + 0];
        float l1 = ay[b] * invd - vert[base + 1];
        float l2 = az[b] * invd - vert[base + 2];
        out[(size_t)b * N + v] = sqrtf(l0 * l0 + l1 * l1 + l2 * l2);
    }
}

// ---------------- launch ----------------

static inline size_t align256(size_t x) { return (x + 255) & ~(size_t)255; }

extern "C" void kernel_launch(void* const* d_in, const int* in_sizes, int n_in,
                              void* d_out, int out_size, void* d_ws, size_t ws_size,
                              hipStream_t stream) {
    const float* vert  = (const float*)d_in[0];
    const int*   faces = (const int*)d_in[1];
    float*       out   = (float*)d_out;

    int N = out_size / BATCH;      // 500000
    int F = in_sizes[1] / 3;       // 1000000
    int E = 6 * F;
    int NB = (N + (1 << BSHIFT) - 1) >> BSHIFT;   // 489 buckets

    char* ws = (char*)d_ws;

    // Fast-path layout: cursor(32KB) | vh[N*B] uint2 | rec[NB*CAPB] i64
    size_t o_cursor = 0;
    size_t o_vh     = NBUK_MAX * 64;
    size_t o_rec    = o_vh + align256((size_t)N * BATCH * sizeof(uint2));
    size_t need     = o_rec + (size_t)NB * CAPB * 8;

    if (ws_size >= need && N <= 524288 && NB <= NBUK_MAX) {
        int*       cursor = (int*)(ws + o_cursor);
        uint2*     vh     = (uint2*)(ws + o_vh);
        long long* rec    = (long long*)(ws + o_rec);

        (void)hipMemsetAsync(cursor, 0, NBUK_MAX * 64, stream);

        int expB = (F + 1023) / 1024;
        int repB = (N * BATCH + 1023) / 1024;
        expand_repack_kernel<<<expB + repB, 1024, 0, stream>>>(
            faces, cursor, rec, vert, vh, N, F, expB);

        bucket_gather_kernel<<<NB, 1024, 0, stream>>>(cursor, rec, vh, out, N);
        return;
    }

    // ---- compact fp32 fallback (R10-proven correctness path) ----
    int threads = 256;
    int nb = (N + SCAN_TILE - 1) / SCAN_TILE;
    size_t f_cnt   = 0;
    size_t f_off   = align256((size_t)N * 4);
    size_t f_bsums = f_off + align256((size_t)N * 4);
    size_t f_col   = f_bsums + 4096;
    size_t f_rank  = f_col + align256((size_t)E * 4);

    int* cnt   = (int*)(ws + f_cnt);
    int* off   = (int*)(ws + f_off);
    int* bsums = (int*)(ws + f_bsums);
    int* col   = (int*)(ws + f_col);
    int* rank  = (int*)(ws + f_rank);

    (void)hipMemsetAsync(cnt, 0, (size_t)N * 4, stream);

    int cntBlocks = (F + threads - 1) / threads;
    count_only_kernel<<<cntBlocks, threads, 0, stream>>>(faces, cnt, rank, F);
    scan_sums_kernel<<<nb, SCAN_T, 0, stream>>>(cnt, bsums, N);
    scan_apply_kernel<<<nb, SCAN_T, 0, stream>>>(cnt, off, bsums, N, nb);
    fill_kernel<<<cntBlocks, threads, 0, stream>>>(faces, off, rank, col, F);
    gather_scalar_kernel<<<(N + threads - 1) / threads, threads, 0, stream>>>(
        vert, cnt, off, col, out, N);
}